// Round 1
// baseline (50.941 us; speedup 1.0000x reference)
//
#include <hip/hip_runtime.h>

// LIF forward over time-major x: (T=16, B=128, N=16384) fp32.
//   m[t] = 0.5*v[t-1] + x[t];  y[t] = (m >= 1.0);  v[t] = m*(1-y[t])
// Independent per (b,n) column -> one thread per float4 column, full T unroll.

#define LIF_T 16
#define TAU 0.5f
#define VTH 1.0f

__global__ __launch_bounds__(256) void lif_fwd_kernel(
    const float4* __restrict__ x, float4* __restrict__ y, int cols) {
    int i = blockIdx.x * blockDim.x + threadIdx.x;
    if (i >= cols) return;

    float vx = 0.0f, vy = 0.0f, vz = 0.0f, vw = 0.0f;
    size_t idx = (size_t)i;

#pragma unroll
    for (int t = 0; t < LIF_T; ++t) {
        float4 xt = x[idx];

        float mx = vx * TAU + xt.x;
        float my = vy * TAU + xt.y;
        float mz = vz * TAU + xt.z;
        float mw = vw * TAU + xt.w;

        float4 out;
        out.x = (mx >= VTH) ? 1.0f : 0.0f;
        out.y = (my >= VTH) ? 1.0f : 0.0f;
        out.z = (mz >= VTH) ? 1.0f : 0.0f;
        out.w = (mw >= VTH) ? 1.0f : 0.0f;

        vx = (mx >= VTH) ? 0.0f : mx;   // hard reset
        vy = (my >= VTH) ? 0.0f : my;
        vz = (mz >= VTH) ? 0.0f : mz;
        vw = (mw >= VTH) ? 0.0f : mw;

        y[idx] = out;
        idx += (size_t)cols;
    }
}

extern "C" void kernel_launch(void* const* d_in, const int* in_sizes, int n_in,
                              void* d_out, int out_size, void* d_ws, size_t ws_size,
                              hipStream_t stream) {
    const float4* x = (const float4*)d_in[0];
    float4* y = (float4*)d_out;

    // total elems = T*B*N; T fixed at 16 per reference; 4 elems per thread.
    int total = in_sizes[0];
    int cols = total / LIF_T / 4;   // float4 columns per time plane

    const int block = 256;
    int grid = (cols + block - 1) / block;
    lif_fwd_kernel<<<grid, block, 0, stream>>>(x, y, cols);
}

// Round 3
// 49.270 us; speedup vs baseline: 1.0339x; 1.0339x over previous
//
#include <hip/hip_runtime.h>

// LIF forward over time-major x: (T=16, B=128, N=16384) fp32.
//   m[t] = 0.5*v[t-1] + x[t];  y[t] = (m >= 1.0);  v[t] = m*(1-y[t])
// One thread per 4-wide column, full T unroll.
// R2: nontemporal stores via native clang vector type (HIP_vector_type
// is a struct and rejected by the builtin). Goal: y's streaming stores
// stop evicting x from the Infinity Cache across graph replays.

#define LIF_T 16
#define TAU 0.5f
#define VTH 1.0f

typedef float fx4 __attribute__((ext_vector_type(4)));

__global__ __launch_bounds__(256) void lif_fwd_kernel(
    const fx4* __restrict__ x, fx4* __restrict__ y, int cols) {
    int i = blockIdx.x * blockDim.x + threadIdx.x;
    if (i >= cols) return;

    fx4 v = {0.0f, 0.0f, 0.0f, 0.0f};
    size_t idx = (size_t)i;

#pragma unroll
    for (int t = 0; t < LIF_T; ++t) {
        fx4 xt = x[idx];

        fx4 m = v * TAU + xt;

        fx4 out;
        out.x = (m.x >= VTH) ? 1.0f : 0.0f;
        out.y = (m.y >= VTH) ? 1.0f : 0.0f;
        out.z = (m.z >= VTH) ? 1.0f : 0.0f;
        out.w = (m.w >= VTH) ? 1.0f : 0.0f;

        v.x = (m.x >= VTH) ? 0.0f : m.x;   // hard reset
        v.y = (m.y >= VTH) ? 0.0f : m.y;
        v.z = (m.z >= VTH) ? 0.0f : m.z;
        v.w = (m.w >= VTH) ? 0.0f : m.w;

        __builtin_nontemporal_store(out, &y[idx]);
        idx += (size_t)cols;
    }
}

extern "C" void kernel_launch(void* const* d_in, const int* in_sizes, int n_in,
                              void* d_out, int out_size, void* d_ws, size_t ws_size,
                              hipStream_t stream) {
    const fx4* x = (const fx4*)d_in[0];
    fx4* y = (fx4*)d_out;

    int total = in_sizes[0];
    int cols = total / LIF_T / 4;   // 4-wide columns per time plane

    const int block = 256;
    int grid = (cols + block - 1) / block;
    lif_fwd_kernel<<<grid, block, 0, stream>>>(x, y, cols);
}

// Round 4
// 49.128 us; speedup vs baseline: 1.0369x; 1.0029x over previous
//
#include <hip/hip_runtime.h>

// LIF forward over time-major x: (T=16, B=128, N=16384) fp32.
//   m[t] = 0.5*v[t-1] + x[t];  y[t] = (m >= 1.0);  v[t] = m*(1-y[t])
// R3: 2 independent float4 columns per thread (split at stride `half`,
// both streams wave-coalesced) to double memory-level parallelism.
// Traffic is fixed (~197 MB/replay); we were at 4.0/6.3 TB/s.

#define LIF_T 16
#define TAU 0.5f
#define VTH 1.0f

typedef float fx4 __attribute__((ext_vector_type(4)));

__device__ __forceinline__ fx4 lif_step(fx4& v, fx4 xt) {
    fx4 m = v * TAU + xt;
    fx4 out;
    out.x = (m.x >= VTH) ? 1.0f : 0.0f;
    out.y = (m.y >= VTH) ? 1.0f : 0.0f;
    out.z = (m.z >= VTH) ? 1.0f : 0.0f;
    out.w = (m.w >= VTH) ? 1.0f : 0.0f;
    v.x = (m.x >= VTH) ? 0.0f : m.x;   // hard reset
    v.y = (m.y >= VTH) ? 0.0f : m.y;
    v.z = (m.z >= VTH) ? 0.0f : m.z;
    v.w = (m.w >= VTH) ? 0.0f : m.w;
    return out;
}

__global__ __launch_bounds__(256) void lif_fwd_kernel(
    const fx4* __restrict__ x, fx4* __restrict__ y, int cols, int half) {
    int i = blockIdx.x * blockDim.x + threadIdx.x;
    if (i >= half) return;

    fx4 v0 = {0.0f, 0.0f, 0.0f, 0.0f};
    fx4 v1 = {0.0f, 0.0f, 0.0f, 0.0f};
    size_t ia = (size_t)i;
    size_t ib = (size_t)i + (size_t)half;

#pragma unroll
    for (int t = 0; t < LIF_T; ++t) {
        fx4 xa = x[ia];
        fx4 xb = x[ib];
        fx4 oa = lif_step(v0, xa);
        fx4 ob = lif_step(v1, xb);
        __builtin_nontemporal_store(oa, &y[ia]);
        __builtin_nontemporal_store(ob, &y[ib]);
        ia += (size_t)cols;
        ib += (size_t)cols;
    }
}

extern "C" void kernel_launch(void* const* d_in, const int* in_sizes, int n_in,
                              void* d_out, int out_size, void* d_ws, size_t ws_size,
                              hipStream_t stream) {
    const fx4* x = (const fx4*)d_in[0];
    fx4* y = (fx4*)d_out;

    int total = in_sizes[0];
    int cols = total / LIF_T / 4;   // float4 columns per time plane
    int half = cols / 2;            // 2 columns per thread

    const int block = 256;
    int grid = (half + block - 1) / block;
    lif_fwd_kernel<<<grid, block, 0, stream>>>(x, y, cols, half);
}